// Round 1
// baseline (24189.798 us; speedup 1.0000x reference)
//
#include <hip/hip_runtime.h>

// LSTM b=32, t=1024, din=512, hid=1024. Persistent cooperative kernel:
// 128 blocks x 256 threads, each block owns 8 hidden units (32 gate cols),
// weights (K=1536 x 32 cols, bf16) resident in LDS. Per step: MFMA GEMM
// [32,1536]x[1536,32] with 4-wave K-split, flag-based all-to-all h exchange.

#define T_STEPS 1024
#define BATCH   32
#define DIN     512
#define HID     1024
#define KTOT    1536
#define NBLK    128
#define WCOLS   32          // gate cols per block
#define WSTR    1544        // shorts per col in LDS (1536 + 8 pad -> 2-way max conflict)
#define REDSTR  33          // padded fp32 reduction row stride
#define REDW    (32*REDSTR) // floats per wave in reduction buffer

#define LDS_W_BYTES   (WCOLS*WSTR*2)        // 98816
#define LDS_RED_BYTES (4*REDW*4)            // 16896
#define LDS_TOTAL     (LDS_W_BYTES + LDS_RED_BYTES)  // 115712

typedef __attribute__((ext_vector_type(8))) short  short8;
typedef __attribute__((ext_vector_type(4))) float  floatx4;
typedef __attribute__((ext_vector_type(4))) unsigned short ushort4_;

__device__ __forceinline__ unsigned short f2bf(float f) {
    unsigned u = __builtin_bit_cast(unsigned, f);
    u += 0x7FFFu + ((u >> 16) & 1u);
    return (unsigned short)(u >> 16);
}
__device__ __forceinline__ float sigf(float x) { return 1.f / (1.f + __expf(-x)); }

// ---- prep: kernel [1536][4096] fp32 -> wt [4096 cols][1536 k] bf16 (transposed) ----
__global__ __launch_bounds__(256) void prep_wt(const float* __restrict__ kern,
                                               unsigned short* __restrict__ wt) {
    __shared__ unsigned short tile[64][72];
    const int c0 = (blockIdx.x & 63) * 64;   // 4096/64 = 64 col tiles
    const int k0 = (blockIdx.x >> 6) * 64;   // 1536/64 = 24 k tiles
    const int cl = threadIdx.x & 63;
    const int kg = threadIdx.x >> 6;         // 0..3
    #pragma unroll
    for (int i = 0; i < 16; ++i) {
        int kl = kg * 16 + i;
        tile[cl][kl] = f2bf(kern[(k0 + kl) * 4096 + c0 + cl]);  // coalesced read
    }
    __syncthreads();
    #pragma unroll
    for (int i = 0; i < 16; ++i) {
        int cc = kg * 16 + i;
        wt[(size_t)(c0 + cc) * KTOT + k0 + cl] = tile[cc][cl];  // coalesced-ish write
    }
}

// ---- prep: x [32][1024][512] fp32 -> xT [1024][32][512] bf16 ----
__global__ __launch_bounds__(256) void prep_x(const float* __restrict__ x,
                                              unsigned short* __restrict__ xT) {
    const int row = blockIdx.x * 2 + (threadIdx.x >> 7);  // row = b*1024 + t
    const int l   = threadIdx.x & 127;
    const int b = row >> 10, t = row & 1023;
    float4 v = ((const float4*)(x + (size_t)row * DIN))[l];
    ushort4_ o;
    o.x = f2bf(v.x); o.y = f2bf(v.y); o.z = f2bf(v.z); o.w = f2bf(v.w);
    *(ushort4_*)(xT + ((size_t)t * BATCH + b) * DIN + l * 4) = o;
}

// ---- prep: h0 = tile(h_init) -> hbuf[0] bf16; zero flags ----
__global__ __launch_bounds__(256) void init_h(const float* __restrict__ h_init,
                                              unsigned short* __restrict__ hbuf,
                                              int* __restrict__ flags) {
    if (blockIdx.x == 32) {
        if (threadIdx.x < NBLK) flags[threadIdx.x] = 0;
        return;
    }
    const int b = blockIdx.x;
    for (int u = threadIdx.x; u < HID; u += 256)
        hbuf[b * HID + u] = f2bf(h_init[u]);
}

// ---- persistent LSTM ----
__global__ __launch_bounds__(256, 1) void lstm_persist(
    const unsigned short* __restrict__ wt,   // [4096][1536] bf16
    const unsigned short* __restrict__ xT,   // [1024][32][512] bf16
    unsigned short* __restrict__ hbuf,       // [2][32][1024] bf16
    int* __restrict__ flags,                 // [128]
    const float* __restrict__ bias,          // [4096]
    float* __restrict__ out)                 // [32][1024][1024] fp32
{
    extern __shared__ char smem[];
    unsigned short* ldsW = (unsigned short*)smem;
    float* red = (float*)(smem + LDS_W_BYTES);

    const int bk   = blockIdx.x;
    const int tid  = threadIdx.x;
    const int wave = tid >> 6;
    const int lane = tid & 63;
    const int lrow = lane & 15;   // m (batch) / n (col) index within 16-tile
    const int kq   = lane >> 4;   // k quad, each holds 8 contiguous k

    // Stage this block's 32 weight columns into LDS: cols {g*1024 + bk*8 + u}
    for (int cl = wave; cl < WCOLS; cl += 4) {
        const int gcol = (cl >> 3) * HID + bk * 8 + (cl & 7);
        const unsigned short* src = wt + (size_t)gcol * KTOT;
        unsigned short* dst = ldsW + cl * WSTR;
        for (int k = lane * 8; k < KTOT; k += 512)
            *(short8*)(dst + k) = *(const short8*)(src + k);
    }

    // Pointwise thread mapping: thread = (batch pb, unit-offset pu)
    const int pb = tid >> 3;
    const int pu = tid & 7;
    float bias_r[4];
    #pragma unroll
    for (int g = 0; g < 4; ++g) bias_r[g] = bias[g * HID + bk * 8 + pu];
    float c_state = 0.f;
    __syncthreads();

    for (int t = 0; t < T_STEPS; ++t) {
        floatx4 zero = {0.f, 0.f, 0.f, 0.f};
        floatx4 acc[2][2];
        acc[0][0] = zero; acc[0][1] = zero; acc[1][0] = zero; acc[1][1] = zero;

        // ---- x-part of K (k in [0,512)) — independent of h, compute BEFORE poll ----
        const unsigned short* xb = xT + (size_t)t * (BATCH * DIN);
        #pragma unroll
        for (int i = 0; i < 4; ++i) {
            const int kl = wave * 128 + i * 32 + kq * 8;
            short8 a0 = *(const short8*)(xb + lrow * DIN + kl);
            short8 a1 = *(const short8*)(xb + (lrow + 16) * DIN + kl);
            short8 b0 = *(const short8*)(ldsW + lrow * WSTR + kl);
            short8 b1 = *(const short8*)(ldsW + (lrow + 16) * WSTR + kl);
            acc[0][0] = __builtin_amdgcn_mfma_f32_16x16x32_bf16(a0, b0, acc[0][0], 0, 0, 0);
            acc[0][1] = __builtin_amdgcn_mfma_f32_16x16x32_bf16(a0, b1, acc[0][1], 0, 0, 0);
            acc[1][0] = __builtin_amdgcn_mfma_f32_16x16x32_bf16(a1, b0, acc[1][0], 0, 0, 0);
            acc[1][1] = __builtin_amdgcn_mfma_f32_16x16x32_bf16(a1, b1, acc[1][1], 0, 0, 0);
        }

        // ---- wait for all h slices of step t ----
        if (t > 0 && tid < NBLK) {
            const int* fl = flags + tid;
            while (__hip_atomic_load(fl, __ATOMIC_RELAXED, __HIP_MEMORY_SCOPE_AGENT) < t)
                __builtin_amdgcn_s_sleep(1);
        }
        __threadfence();     // acquire: invalidate L1/L2 so h loads see fresh data
        __syncthreads();     // conjoin: every flag observed by someone in this block

        // ---- h-part of K (k in [512,1536)) ----
        const unsigned short* hb = hbuf + (size_t)(t & 1) * (BATCH * HID);
        #pragma unroll
        for (int i = 0; i < 8; ++i) {
            const int kh = wave * 256 + i * 32 + kq * 8;  // 0..1023
            const int kw = 512 + kh;
            short8 a0 = *(const short8*)(hb + lrow * HID + kh);
            short8 a1 = *(const short8*)(hb + (lrow + 16) * HID + kh);
            short8 b0 = *(const short8*)(ldsW + lrow * WSTR + kw);
            short8 b1 = *(const short8*)(ldsW + (lrow + 16) * WSTR + kw);
            acc[0][0] = __builtin_amdgcn_mfma_f32_16x16x32_bf16(a0, b0, acc[0][0], 0, 0, 0);
            acc[0][1] = __builtin_amdgcn_mfma_f32_16x16x32_bf16(a0, b1, acc[0][1], 0, 0, 0);
            acc[1][0] = __builtin_amdgcn_mfma_f32_16x16x32_bf16(a1, b0, acc[1][0], 0, 0, 0);
            acc[1][1] = __builtin_amdgcn_mfma_f32_16x16x32_bf16(a1, b1, acc[1][1], 0, 0, 0);
        }

        // ---- cross-wave K reduction via LDS ----
        #pragma unroll
        for (int mt = 0; mt < 2; ++mt)
            #pragma unroll
            for (int nt = 0; nt < 2; ++nt)
                #pragma unroll
                for (int r = 0; r < 4; ++r) {
                    const int row = mt * 16 + kq * 4 + r;   // C/D: row=(lane>>4)*4+reg
                    const int col = nt * 16 + lrow;         //      col=lane&15
                    red[wave * REDW + row * REDSTR + col] = acc[mt][nt][r];
                }
        __syncthreads();

        // ---- pointwise: gates -> c,h ----
        float gv[4];
        #pragma unroll
        for (int g = 0; g < 4; ++g) {
            const int col = g * 8 + pu;
            float s = bias_r[g];
            #pragma unroll
            for (int w = 0; w < 4; ++w) s += red[w * REDW + pb * REDSTR + col];
            gv[g] = s;
        }
        const float fg = sigf(gv[0]);
        const float ig = sigf(gv[1]);
        const float og = sigf(gv[2]);
        const float gg = tanhf(gv[3]);
        c_state = fg * c_state + ig * gg;
        const float hn = og * tanhf(c_state);

        out[(size_t)pb * (T_STEPS * HID) + (size_t)t * HID + bk * 8 + pu] = hn;
        hbuf[(size_t)((t + 1) & 1) * (BATCH * HID) + pb * HID + bk * 8 + pu] = f2bf(hn);

        // ---- publish ----
        __threadfence();   // each thread flushes its own h/out stores
        __syncthreads();   // all flushed before flag; also protects red reuse
        if (tid == 0)
            __hip_atomic_store(flags + bk, t + 1, __ATOMIC_RELAXED, __HIP_MEMORY_SCOPE_AGENT);
    }
}

extern "C" void kernel_launch(void* const* d_in, const int* in_sizes, int n_in,
                              void* d_out, int out_size, void* d_ws, size_t ws_size,
                              hipStream_t stream) {
    (void)in_sizes; (void)n_in; (void)out_size;
    const float* x      = (const float*)d_in[0];
    // d_in[1] = input_paddings (all zero, unused per reference)
    const float* kern   = (const float*)d_in[2];
    const float* bias   = (const float*)d_in[3];
    const float* h_init = (const float*)d_in[4];
    float* out = (float*)d_out;

    char* ws = (char*)d_ws;
    // ws layout (needs ~44.2 MB)
    unsigned short* wt    = (unsigned short*)(ws);                       // 12,582,912 B
    unsigned short* xT    = (unsigned short*)(ws + 12582912);            // 33,554,432 B
    unsigned short* hbuf  = (unsigned short*)(ws + 12582912 + 33554432); //    131,072 B
    int*            flags = (int*)(ws + 12582912 + 33554432 + 131072);   //        512 B
    (void)ws_size;

    hipFuncSetAttribute((const void*)lstm_persist,
                        hipFuncAttributeMaxDynamicSharedMemorySize, LDS_TOTAL);

    prep_wt<<<dim3(64 * 24), dim3(256), 0, stream>>>(kern, wt);
    prep_x<<<dim3(BATCH * T_STEPS / 2), dim3(256), 0, stream>>>(x, xT);
    init_h<<<dim3(33), dim3(256), 0, stream>>>(h_init, hbuf, flags);

    void* args[] = { &wt, &xT, &hbuf, &flags, &bias, &out };
    hipLaunchCooperativeKernel((const void*)lstm_persist, dim3(NBLK), dim3(256),
                               args, LDS_TOTAL, stream);
}

// Round 2
// 5329.454 us; speedup vs baseline: 4.5389x; 4.5389x over previous
//
#include <hip/hip_runtime.h>

// LSTM b=32, t=1024, din=512, hid=1024. Persistent cooperative kernel:
// 128 blocks x 256 threads, each block owns 8 hidden units (32 gate cols),
// weights (K=1536 x 32 cols, bf16) resident in LDS. Per step: MFMA GEMM
// [32,1536]x[1536,32] with 4-wave K-split.
//
// R2: h exchange via sc0/sc1 (system-coherent, L3 coherence point) inline-asm
// loads/stores + s_waitcnt vmcnt(0) release — NO __threadfence (which emitted
// buffer_wbl2/buffer_inv = full-L2 flush per step and caused the 24 ms R1).

#define T_STEPS 1024
#define BATCH   32
#define DIN     512
#define HID     1024
#define KTOT    1536
#define NBLK    128
#define WCOLS   32          // gate cols per block
#define WSTR    1544        // shorts per col in LDS (1536 + 8 pad -> 2-way max conflict)
#define REDSTR  33          // padded fp32 reduction row stride
#define REDW    (32*REDSTR) // floats per wave in reduction buffer

#define LDS_W_BYTES   (WCOLS*WSTR*2)        // 98816
#define LDS_RED_BYTES (4*REDW*4)            // 16896
#define LDS_TOTAL     (LDS_W_BYTES + LDS_RED_BYTES)  // 115712

typedef __attribute__((ext_vector_type(8))) short  short8;
typedef __attribute__((ext_vector_type(4))) float  floatx4;
typedef __attribute__((ext_vector_type(4))) unsigned short ushort4_;

__device__ __forceinline__ unsigned short f2bf(float f) {
    unsigned u = __builtin_bit_cast(unsigned, f);
    u += 0x7FFFu + ((u >> 16) & 1u);
    return (unsigned short)(u >> 16);
}
__device__ __forceinline__ float sigf(float x) { return 1.f / (1.f + __expf(-x)); }

// ---- coherent (L3 coherence-point) access helpers: bypass L1+L2 via sc0 sc1 ----
__device__ __forceinline__ floatx4 coh_load16(const void* p) {
    floatx4 v;
    asm volatile("global_load_dwordx4 %0, %1, off sc0 sc1" : "=v"(v) : "v"(p));
    return v;
}
__device__ __forceinline__ int coh_load4(const void* p) {
    int v;
    asm volatile("global_load_dword %0, %1, off sc0 sc1\n\ts_waitcnt vmcnt(0)"
                 : "=v"(v) : "v"(p) : "memory");
    return v;
}
__device__ __forceinline__ void coh_store2(void* p, unsigned short v) {
    asm volatile("global_store_short %0, %1, off sc0 sc1" :: "v"(p), "v"((unsigned)v) : "memory");
}
__device__ __forceinline__ void coh_store4(void* p, int v) {
    asm volatile("global_store_dword %0, %1, off sc0 sc1" :: "v"(p), "v"(v) : "memory");
}
__device__ __forceinline__ void wait_vm0() {
    asm volatile("s_waitcnt vmcnt(0)" ::: "memory");
}

// ---- prep: kernel [1536][4096] fp32 -> wt [4096 cols][1536 k] bf16 (transposed) ----
__global__ __launch_bounds__(256) void prep_wt(const float* __restrict__ kern,
                                               unsigned short* __restrict__ wt) {
    __shared__ unsigned short tile[64][72];
    const int c0 = (blockIdx.x & 63) * 64;   // 4096/64 = 64 col tiles
    const int k0 = (blockIdx.x >> 6) * 64;   // 1536/64 = 24 k tiles
    const int cl = threadIdx.x & 63;
    const int kg = threadIdx.x >> 6;         // 0..3
    #pragma unroll
    for (int i = 0; i < 16; ++i) {
        int kl = kg * 16 + i;
        tile[cl][kl] = f2bf(kern[(k0 + kl) * 4096 + c0 + cl]);  // coalesced read
    }
    __syncthreads();
    #pragma unroll
    for (int i = 0; i < 16; ++i) {
        int cc = kg * 16 + i;
        wt[(size_t)(c0 + cc) * KTOT + k0 + cl] = tile[cc][cl];  // coalesced-ish write
    }
}

// ---- prep: x [32][1024][512] fp32 -> xT [1024][32][512] bf16 ----
__global__ __launch_bounds__(256) void prep_x(const float* __restrict__ x,
                                              unsigned short* __restrict__ xT) {
    const int row = blockIdx.x * 2 + (threadIdx.x >> 7);  // row = b*1024 + t
    const int l   = threadIdx.x & 127;
    const int b = row >> 10, t = row & 1023;
    float4 v = ((const float4*)(x + (size_t)row * DIN))[l];
    ushort4_ o;
    o.x = f2bf(v.x); o.y = f2bf(v.y); o.z = f2bf(v.z); o.w = f2bf(v.w);
    *(ushort4_*)(xT + ((size_t)t * BATCH + b) * DIN + l * 4) = o;
}

// ---- prep: h0 = tile(h_init) -> hbuf[0] bf16; zero flags ----
__global__ __launch_bounds__(256) void init_h(const float* __restrict__ h_init,
                                              unsigned short* __restrict__ hbuf,
                                              int* __restrict__ flags) {
    if (blockIdx.x == 32) {
        if (threadIdx.x < NBLK) flags[threadIdx.x] = 0;
        return;
    }
    const int b = blockIdx.x;
    for (int u = threadIdx.x; u < HID; u += 256)
        hbuf[b * HID + u] = f2bf(h_init[u]);
}

// ---- persistent LSTM ----
__global__ __launch_bounds__(256, 1) void lstm_persist(
    const unsigned short* __restrict__ wt,   // [4096][1536] bf16
    const unsigned short* __restrict__ xT,   // [1024][32][512] bf16
    unsigned short* __restrict__ hbuf,       // [2][32][1024] bf16
    int* __restrict__ flags,                 // [128]
    const float* __restrict__ bias,          // [4096]
    float* __restrict__ out)                 // [32][1024][1024] fp32
{
    extern __shared__ char smem[];
    unsigned short* ldsW = (unsigned short*)smem;
    float* red = (float*)(smem + LDS_W_BYTES);

    const int bk   = blockIdx.x;
    const int tid  = threadIdx.x;
    const int wave = tid >> 6;
    const int lane = tid & 63;
    const int lrow = lane & 15;   // m (batch) / n (col) index within 16-tile
    const int kq   = lane >> 4;   // k quad, each holds 8 contiguous k

    // Stage this block's 32 weight columns into LDS: cols {g*1024 + bk*8 + u}
    for (int cl = wave; cl < WCOLS; cl += 4) {
        const int gcol = (cl >> 3) * HID + bk * 8 + (cl & 7);
        const unsigned short* src = wt + (size_t)gcol * KTOT;
        unsigned short* dst = ldsW + cl * WSTR;
        for (int k = lane * 8; k < KTOT; k += 512)
            *(short8*)(dst + k) = *(const short8*)(src + k);
    }

    // Pointwise thread mapping: thread = (batch pb, unit-offset pu)
    const int pb = tid >> 3;
    const int pu = tid & 7;
    float bias_r[4];
    #pragma unroll
    for (int g = 0; g < 4; ++g) bias_r[g] = bias[g * HID + bk * 8 + pu];
    float c_state = 0.f;
    __syncthreads();

    for (int t = 0; t < T_STEPS; ++t) {
        floatx4 zero = {0.f, 0.f, 0.f, 0.f};
        floatx4 acc[2][2];
        acc[0][0] = zero; acc[0][1] = zero; acc[1][0] = zero; acc[1][1] = zero;

        // ---- x-part of K (k in [0,512)) — independent of h, compute BEFORE poll ----
        const unsigned short* xb = xT + (size_t)t * (BATCH * DIN);
        #pragma unroll
        for (int i = 0; i < 4; ++i) {
            const int kl = wave * 128 + i * 32 + kq * 8;
            short8 a0 = *(const short8*)(xb + lrow * DIN + kl);
            short8 a1 = *(const short8*)(xb + (lrow + 16) * DIN + kl);
            short8 b0 = *(const short8*)(ldsW + lrow * WSTR + kl);
            short8 b1 = *(const short8*)(ldsW + (lrow + 16) * WSTR + kl);
            acc[0][0] = __builtin_amdgcn_mfma_f32_16x16x32_bf16(a0, b0, acc[0][0], 0, 0, 0);
            acc[0][1] = __builtin_amdgcn_mfma_f32_16x16x32_bf16(a0, b1, acc[0][1], 0, 0, 0);
            acc[1][0] = __builtin_amdgcn_mfma_f32_16x16x32_bf16(a1, b0, acc[1][0], 0, 0, 0);
            acc[1][1] = __builtin_amdgcn_mfma_f32_16x16x32_bf16(a1, b1, acc[1][1], 0, 0, 0);
        }

        // ---- wait for all h slices of step t (coherent flag poll, no fences) ----
        if (t > 0 && tid < NBLK) {
            const int* fl = flags + tid;
            while (coh_load4(fl) < t)
                __builtin_amdgcn_s_sleep(1);
        }
        __syncthreads();     // every flag observed by someone in this block

        // ---- h-part of K (k in [512,1536)): issue ALL coherent loads, one wait ----
        const unsigned short* hb = hbuf + (size_t)(t & 1) * (BATCH * HID);
        floatx4 ha[8][2];
        #pragma unroll
        for (int i = 0; i < 8; ++i) {
            const int kh = wave * 256 + i * 32 + kq * 8;  // 0..1023
            ha[i][0] = coh_load16(hb + lrow * HID + kh);
            ha[i][1] = coh_load16(hb + (lrow + 16) * HID + kh);
        }
        wait_vm0();
        #pragma unroll
        for (int i = 0; i < 8; ++i) {
            const int kw = 512 + wave * 256 + i * 32 + kq * 8;
            short8 a0 = __builtin_bit_cast(short8, ha[i][0]);
            short8 a1 = __builtin_bit_cast(short8, ha[i][1]);
            short8 b0 = *(const short8*)(ldsW + lrow * WSTR + kw);
            short8 b1 = *(const short8*)(ldsW + (lrow + 16) * WSTR + kw);
            acc[0][0] = __builtin_amdgcn_mfma_f32_16x16x32_bf16(a0, b0, acc[0][0], 0, 0, 0);
            acc[0][1] = __builtin_amdgcn_mfma_f32_16x16x32_bf16(a0, b1, acc[0][1], 0, 0, 0);
            acc[1][0] = __builtin_amdgcn_mfma_f32_16x16x32_bf16(a1, b0, acc[1][0], 0, 0, 0);
            acc[1][1] = __builtin_amdgcn_mfma_f32_16x16x32_bf16(a1, b1, acc[1][1], 0, 0, 0);
        }

        // ---- cross-wave K reduction via LDS ----
        #pragma unroll
        for (int mt = 0; mt < 2; ++mt)
            #pragma unroll
            for (int nt = 0; nt < 2; ++nt)
                #pragma unroll
                for (int r = 0; r < 4; ++r) {
                    const int row = mt * 16 + kq * 4 + r;   // C/D: row=(lane>>4)*4+reg
                    const int col = nt * 16 + lrow;         //      col=lane&15
                    red[wave * REDW + row * REDSTR + col] = acc[mt][nt][r];
                }
        __syncthreads();

        // ---- pointwise: gates -> c,h ----
        float gv[4];
        #pragma unroll
        for (int g = 0; g < 4; ++g) {
            const int col = g * 8 + pu;
            float s = bias_r[g];
            #pragma unroll
            for (int w = 0; w < 4; ++w) s += red[w * REDW + pb * REDSTR + col];
            gv[g] = s;
        }
        const float fg = sigf(gv[0]);
        const float ig = sigf(gv[1]);
        const float og = sigf(gv[2]);
        const float gg = tanhf(gv[3]);
        c_state = fg * c_state + ig * gg;
        const float hn = og * tanhf(c_state);

        out[(size_t)pb * (T_STEPS * HID) + (size_t)t * HID + bk * 8 + pu] = hn;
        unsigned short* hp = hbuf + (size_t)((t + 1) & 1) * (BATCH * HID)
                                  + pb * HID + bk * 8 + pu;
        coh_store2(hp, f2bf(hn));

        // ---- publish: own stores acked at coherence point, barrier, then flag ----
        wait_vm0();        // each wave: h stores (and out store) complete
        __syncthreads();   // all waves flushed before flag; also protects red reuse
        if (tid == 0)
            coh_store4(flags + bk, t + 1);
    }
}

extern "C" void kernel_launch(void* const* d_in, const int* in_sizes, int n_in,
                              void* d_out, int out_size, void* d_ws, size_t ws_size,
                              hipStream_t stream) {
    (void)in_sizes; (void)n_in; (void)out_size;
    const float* x      = (const float*)d_in[0];
    // d_in[1] = input_paddings (all zero, unused per reference)
    const float* kern   = (const float*)d_in[2];
    const float* bias   = (const float*)d_in[3];
    const float* h_init = (const float*)d_in[4];
    float* out = (float*)d_out;

    char* ws = (char*)d_ws;
    // ws layout (needs ~44.2 MB)
    unsigned short* wt    = (unsigned short*)(ws);                       // 12,582,912 B
    unsigned short* xT    = (unsigned short*)(ws + 12582912);            // 33,554,432 B
    unsigned short* hbuf  = (unsigned short*)(ws + 12582912 + 33554432); //    131,072 B
    int*            flags = (int*)(ws + 12582912 + 33554432 + 131072);   //        512 B
    (void)ws_size;

    hipFuncSetAttribute((const void*)lstm_persist,
                        hipFuncAttributeMaxDynamicSharedMemorySize, LDS_TOTAL);

    prep_wt<<<dim3(64 * 24), dim3(256), 0, stream>>>(kern, wt);
    prep_x<<<dim3(BATCH * T_STEPS / 2), dim3(256), 0, stream>>>(x, xT);
    init_h<<<dim3(33), dim3(256), 0, stream>>>(h_init, hbuf, flags);

    void* args[] = { &wt, &xT, &hbuf, &flags, &bias, &out };
    hipLaunchCooperativeKernel((const void*)lstm_persist, dim3(NBLK), dim3(256),
                               args, LDS_TOTAL, stream);
}

// Round 3
// 5019.756 us; speedup vs baseline: 4.8189x; 1.0617x over previous
//
#include <hip/hip_runtime.h>

// LSTM b=32, t=1024, din=512, hid=1024. Persistent cooperative kernel:
// 128 blocks x 256 threads, each block owns 8 hidden units (32 gate cols),
// weights (K=1536 x 32 cols, bf16) resident in LDS. Per step: MFMA GEMM
// [32,1536]x[1536,32] with 4-wave K-split.
//
// R3: (a) sc1 (device scope, L3 coherence point) instead of sc0 sc1 (system
// scope -> HBM round trips; R2's WRITE_SIZE showed hbuf punched to HBM).
// (b) publish path = LDS-gather + 32x16B stores by wave 0 only, vmcnt(0),
// flag; 'out' store off the ack path. (c) per-wave poll of only its 32
// producer blocks' flags, no barrier between poll and h-load.

#define T_STEPS 1024
#define BATCH   32
#define DIN     512
#define HID     1024
#define KTOT    1536
#define NBLK    128
#define WCOLS   32          // gate cols per block
#define WSTR    1544        // shorts per col in LDS (1536 + 8 pad -> 2-way max conflict)
#define REDSTR  33          // padded fp32 reduction row stride
#define REDW    (32*REDSTR) // floats per wave in reduction buffer

#define LDS_W_BYTES   (WCOLS*WSTR*2)        // 98816
#define LDS_RED_BYTES (4*REDW*4)            // 16896
#define LDS_H_BYTES   (256*2)               // 512: per-step h gather
#define LDS_TOTAL     (LDS_W_BYTES + LDS_RED_BYTES + LDS_H_BYTES)

typedef __attribute__((ext_vector_type(8))) short  short8;
typedef __attribute__((ext_vector_type(4))) float  floatx4;
typedef __attribute__((ext_vector_type(4))) unsigned short ushort4_;

__device__ __forceinline__ unsigned short f2bf(float f) {
    unsigned u = __builtin_bit_cast(unsigned, f);
    u += 0x7FFFu + ((u >> 16) & 1u);
    return (unsigned short)(u >> 16);
}
__device__ __forceinline__ float sigf(float x) { return 1.f / (1.f + __expf(-x)); }

// ---- device-scope (L3 coherence point) access helpers: sc1 ----
__device__ __forceinline__ floatx4 coh_load16(const void* p) {
    floatx4 v;
    asm volatile("global_load_dwordx4 %0, %1, off sc1" : "=v"(v) : "v"(p));
    return v;
}
__device__ __forceinline__ int coh_load4(const void* p) {
    int v;
    asm volatile("global_load_dword %0, %1, off sc1\n\ts_waitcnt vmcnt(0)"
                 : "=v"(v) : "v"(p) : "memory");
    return v;
}
__device__ __forceinline__ void coh_store16(void* p, short8 v) {
    asm volatile("global_store_dwordx4 %0, %1, off sc1" :: "v"(p), "v"(v) : "memory");
}
__device__ __forceinline__ void coh_store4(void* p, int v) {
    asm volatile("global_store_dword %0, %1, off sc1" :: "v"(p), "v"(v) : "memory");
}
__device__ __forceinline__ void wait_vm0() {
    asm volatile("s_waitcnt vmcnt(0)" ::: "memory");
}

// ---- prep: kernel [1536][4096] fp32 -> wt [4096 cols][1536 k] bf16 (transposed) ----
__global__ __launch_bounds__(256) void prep_wt(const float* __restrict__ kern,
                                               unsigned short* __restrict__ wt) {
    __shared__ unsigned short tile[64][72];
    const int c0 = (blockIdx.x & 63) * 64;   // 4096/64 = 64 col tiles
    const int k0 = (blockIdx.x >> 6) * 64;   // 1536/64 = 24 k tiles
    const int cl = threadIdx.x & 63;
    const int kg = threadIdx.x >> 6;         // 0..3
    #pragma unroll
    for (int i = 0; i < 16; ++i) {
        int kl = kg * 16 + i;
        tile[cl][kl] = f2bf(kern[(k0 + kl) * 4096 + c0 + cl]);  // coalesced read
    }
    __syncthreads();
    #pragma unroll
    for (int i = 0; i < 16; ++i) {
        int cc = kg * 16 + i;
        wt[(size_t)(c0 + cc) * KTOT + k0 + cl] = tile[cc][cl];  // coalesced-ish write
    }
}

// ---- prep: x [32][1024][512] fp32 -> xT [1024][32][512] bf16 ----
__global__ __launch_bounds__(256) void prep_x(const float* __restrict__ x,
                                              unsigned short* __restrict__ xT) {
    const int row = blockIdx.x * 2 + (threadIdx.x >> 7);  // row = b*1024 + t
    const int l   = threadIdx.x & 127;
    const int b = row >> 10, t = row & 1023;
    float4 v = ((const float4*)(x + (size_t)row * DIN))[l];
    ushort4_ o;
    o.x = f2bf(v.x); o.y = f2bf(v.y); o.z = f2bf(v.z); o.w = f2bf(v.w);
    *(ushort4_*)(xT + ((size_t)t * BATCH + b) * DIN + l * 4) = o;
}

// ---- prep: h0 = tile(h_init) -> hbuf[0] bf16; zero flags (stride-4 ints) ----
__global__ __launch_bounds__(256) void init_h(const float* __restrict__ h_init,
                                              unsigned short* __restrict__ hbuf,
                                              int* __restrict__ flags) {
    if (blockIdx.x == 32) {
        for (int i = threadIdx.x; i < NBLK * 4; i += 256) flags[i] = 0;
        return;
    }
    const int b = blockIdx.x;
    for (int u = threadIdx.x; u < HID; u += 256)
        hbuf[b * HID + u] = f2bf(h_init[u]);
}

// ---- persistent LSTM ----
__global__ __launch_bounds__(256, 1) void lstm_persist(
    const unsigned short* __restrict__ wt,   // [4096][1536] bf16
    const unsigned short* __restrict__ xT,   // [1024][32][512] bf16
    unsigned short* __restrict__ hbuf,       // [2][32][1024] bf16
    int* __restrict__ flags,                 // [128*4], stride 4 ints (16B)
    const float* __restrict__ bias,          // [4096]
    float* __restrict__ out)                 // [32][1024][1024] fp32
{
    extern __shared__ char smem[];
    unsigned short* ldsW = (unsigned short*)smem;
    float* red = (float*)(smem + LDS_W_BYTES);
    unsigned short* hLDS = (unsigned short*)(smem + LDS_W_BYTES + LDS_RED_BYTES);

    const int bk   = blockIdx.x;
    const int tid  = threadIdx.x;
    const int wave = tid >> 6;
    const int lane = tid & 63;
    const int lrow = lane & 15;   // m (batch) / n (col) index within 16-tile
    const int kq   = lane >> 4;   // k quad, each holds 8 contiguous k

    // Stage this block's 32 weight columns into LDS: cols {g*1024 + bk*8 + u}
    for (int cl = wave; cl < WCOLS; cl += 4) {
        const int gcol = (cl >> 3) * HID + bk * 8 + (cl & 7);
        const unsigned short* src = wt + (size_t)gcol * KTOT;
        unsigned short* dst = ldsW + cl * WSTR;
        for (int k = lane * 8; k < KTOT; k += 512)
            *(short8*)(dst + k) = *(const short8*)(src + k);
    }

    // Pointwise thread mapping: thread = (batch pb, unit-offset pu)
    const int pb = tid >> 3;
    const int pu = tid & 7;
    float bias_r[4];
    #pragma unroll
    for (int g = 0; g < 4; ++g) bias_r[g] = bias[g * HID + bk * 8 + pu];
    float c_state = 0.f;

    // This wave's producer set: h units [wave*256, wave*256+256) = blocks
    // [wave*32, wave*32+32). Two lanes per flag (lane&31).
    const int* myflag = flags + (wave * 32 + (lane & 31)) * 4;
    __syncthreads();

    for (int t = 0; t < T_STEPS; ++t) {
        floatx4 zero = {0.f, 0.f, 0.f, 0.f};
        floatx4 acc[2][2];
        acc[0][0] = zero; acc[0][1] = zero; acc[1][0] = zero; acc[1][1] = zero;

        // ---- x-part of K (k in [0,512)) — independent of h, compute BEFORE poll ----
        const unsigned short* xb = xT + (size_t)t * (BATCH * DIN);
        #pragma unroll
        for (int i = 0; i < 4; ++i) {
            const int kl = wave * 128 + i * 32 + kq * 8;
            short8 a0 = *(const short8*)(xb + lrow * DIN + kl);
            short8 a1 = *(const short8*)(xb + (lrow + 16) * DIN + kl);
            short8 b0 = *(const short8*)(ldsW + lrow * WSTR + kl);
            short8 b1 = *(const short8*)(ldsW + (lrow + 16) * WSTR + kl);
            acc[0][0] = __builtin_amdgcn_mfma_f32_16x16x32_bf16(a0, b0, acc[0][0], 0, 0, 0);
            acc[0][1] = __builtin_amdgcn_mfma_f32_16x16x32_bf16(a0, b1, acc[0][1], 0, 0, 0);
            acc[1][0] = __builtin_amdgcn_mfma_f32_16x16x32_bf16(a1, b0, acc[1][0], 0, 0, 0);
            acc[1][1] = __builtin_amdgcn_mfma_f32_16x16x32_bf16(a1, b1, acc[1][1], 0, 0, 0);
        }

        // ---- wait for THIS WAVE's 32 producer blocks only (no barrier after) ----
        if (t > 0) {
            while (coh_load4(myflag) < t)
                __builtin_amdgcn_s_sleep(1);
        }

        // ---- h-part of K: issue all device-scope loads for this wave's slice ----
        const unsigned short* hb = hbuf + (size_t)(t & 1) * (BATCH * HID);
        floatx4 ha[8][2];
        #pragma unroll
        for (int i = 0; i < 8; ++i) {
            const int kh = wave * 256 + i * 32 + kq * 8;  // 0..1023
            ha[i][0] = coh_load16(hb + lrow * HID + kh);
            ha[i][1] = coh_load16(hb + (lrow + 16) * HID + kh);
        }
        wait_vm0();
        #pragma unroll
        for (int i = 0; i < 8; ++i) {
            const int kw = 512 + wave * 256 + i * 32 + kq * 8;
            short8 a0 = __builtin_bit_cast(short8, ha[i][0]);
            short8 a1 = __builtin_bit_cast(short8, ha[i][1]);
            short8 b0 = *(const short8*)(ldsW + lrow * WSTR + kw);
            short8 b1 = *(const short8*)(ldsW + (lrow + 16) * WSTR + kw);
            acc[0][0] = __builtin_amdgcn_mfma_f32_16x16x32_bf16(a0, b0, acc[0][0], 0, 0, 0);
            acc[0][1] = __builtin_amdgcn_mfma_f32_16x16x32_bf16(a0, b1, acc[0][1], 0, 0, 0);
            acc[1][0] = __builtin_amdgcn_mfma_f32_16x16x32_bf16(a1, b0, acc[1][0], 0, 0, 0);
            acc[1][1] = __builtin_amdgcn_mfma_f32_16x16x32_bf16(a1, b1, acc[1][1], 0, 0, 0);
        }

        // ---- cross-wave K reduction via LDS ----
        #pragma unroll
        for (int mt = 0; mt < 2; ++mt)
            #pragma unroll
            for (int nt = 0; nt < 2; ++nt)
                #pragma unroll
                for (int r = 0; r < 4; ++r) {
                    const int row = mt * 16 + kq * 4 + r;   // C/D: row=(lane>>4)*4+reg
                    const int col = nt * 16 + lrow;         //      col=lane&15
                    red[wave * REDW + row * REDSTR + col] = acc[mt][nt][r];
                }
        __syncthreads();   // barrier A: all partials visible

        // ---- pointwise: gates -> c,h ----
        float gv[4];
        #pragma unroll
        for (int g = 0; g < 4; ++g) {
            const int col = g * 8 + pu;
            float s = bias_r[g];
            #pragma unroll
            for (int w = 0; w < 4; ++w) s += red[w * REDW + pb * REDSTR + col];
            gv[g] = s;
        }
        const float fg = sigf(gv[0]);
        const float ig = sigf(gv[1]);
        const float og = sigf(gv[2]);
        const float gg = tanhf(gv[3]);
        c_state = fg * c_state + ig * gg;
        const float hn = og * tanhf(c_state);

        out[(size_t)pb * (T_STEPS * HID) + (size_t)t * HID + bk * 8 + pu] = hn;
        hLDS[tid] = f2bf(hn);          // [pb][pu] gather for wave-0 publish
        __syncthreads();   // barrier B: hLDS complete; red safe to reuse

        // ---- publish (wave 0 only): 32 x 16B device-scope stores, ack, flag ----
        if (wave == 0) {
            if (lane < 32) {
                short8 v = *(const short8*)(hLDS + lane * 8);
                unsigned short* hp = hbuf + (size_t)((t + 1) & 1) * (BATCH * HID)
                                          + lane * HID + bk * 8;
                coh_store16(hp, v);
            }
            wait_vm0();    // wave 0's h stores acked at L3
            if (lane == 0)
                coh_store4(flags + bk * 4, t + 1);
        }
    }
}

extern "C" void kernel_launch(void* const* d_in, const int* in_sizes, int n_in,
                              void* d_out, int out_size, void* d_ws, size_t ws_size,
                              hipStream_t stream) {
    (void)in_sizes; (void)n_in; (void)out_size;
    const float* x      = (const float*)d_in[0];
    // d_in[1] = input_paddings (all zero, unused per reference)
    const float* kern   = (const float*)d_in[2];
    const float* bias   = (const float*)d_in[3];
    const float* h_init = (const float*)d_in[4];
    float* out = (float*)d_out;

    char* ws = (char*)d_ws;
    // ws layout (needs ~44.3 MB)
    unsigned short* wt    = (unsigned short*)(ws);                       // 12,582,912 B
    unsigned short* xT    = (unsigned short*)(ws + 12582912);            // 33,554,432 B
    unsigned short* hbuf  = (unsigned short*)(ws + 12582912 + 33554432); //    131,072 B
    int*            flags = (int*)(ws + 12582912 + 33554432 + 131072);   //      2,048 B
    (void)ws_size;

    hipFuncSetAttribute((const void*)lstm_persist,
                        hipFuncAttributeMaxDynamicSharedMemorySize, LDS_TOTAL);

    prep_wt<<<dim3(64 * 24), dim3(256), 0, stream>>>(kern, wt);
    prep_x<<<dim3(BATCH * T_STEPS / 2), dim3(256), 0, stream>>>(x, xT);
    init_h<<<dim3(33), dim3(256), 0, stream>>>(h_init, hbuf, flags);

    void* args[] = { &wt, &xT, &hbuf, &flags, &bias, &out };
    hipLaunchCooperativeKernel((const void*)lstm_persist, dim3(NBLK), dim3(256),
                               args, LDS_TOTAL, stream);
}